// Round 6
// baseline (227.667 us; speedup 1.0000x reference)
//
#include <hip/hip_runtime.h>

#define NB 16
#define NC 256
#define NH 64
#define NW 64
#define PATCH 9
#define TROWS 4
#define CHST (NH * NW)          // channel plane stride (floats)
#define DEPTH 4                 // register pipeline depth (per-wave, stride-2 channels)
#define BT 384                  // 6 waves: wv%3 -> di member, wv/3 -> channel parity

// DPP 16-lane-row shifts (CDNA), direction verified on HW in R3:
//   row_shr:1 (0x111): lane l <- lane l-1 (first lane of 16-row -> 0)
//   row_shl:1 (0x101): lane l <- lane l+1 (last  lane of 16-row -> 0)
// 16-lane col-groups == DPP rows, so shifted-in zeros give horizontal
// zero-padding of y for free.
__device__ __forceinline__ float from_prev_lane(float v) {
    return __int_as_float(__builtin_amdgcn_update_dpp(
        0, __float_as_int(v), 0x111, 0xF, 0xF, true));
}
__device__ __forceinline__ float from_next_lane(float v) {
    return __int_as_float(__builtin_amdgcn_update_dpp(
        0, __float_as_int(v), 0x101, 0xF, 0xF, true));
}

// out[b, di*9+dj, i, j] = (1/C) * sum_c x[b,c,i,j] * y[b,c,i+di-4, j+dj-4]
__global__ void __launch_bounds__(BT, 3)   // VGPR<=170 -> 2 blocks/CU (12 waves)
corr_kernel(const float* __restrict__ x, const float* __restrict__ y,
            float* __restrict__ out)
{
    // cross-parity reduction: [dj][192 threads][float4], conflict-free b128
    __shared__ __align__(16) float red[PATCH * 192 * 4];

    const int tid  = threadIdx.x;
    const int wv   = tid >> 6;          // 0..5
    const int ln   = tid & 63;
    const int q    = wv / 3;            // channel parity (c ≡ q mod 2)
    const int w3   = wv % 3;            // member of di triple
    const int prow = ln >> 4;           // pixel row within tile
    const int j0   = (ln & 15) << 2;    // col base, lane order == col order

    // g is the FAST grid dim: the 3 blocks sharing x rows are dispatch-adjacent
    const int blk = blockIdx.x;         // 768 = (b*16 + t)*3 + g
    const int g   = blk % 3;
    const int bt  = blk / 3;
    const int b   = bt >> 4;
    const int t   = bt & 15;
    const int r0  = t * TROWS;

    const int di  = g * 3 + w3;         // 0..8, wave-uniform
    const int i   = r0 + prow;          // output pixel row
    const int yr0 = i + di - 4;         // y row this thread needs
    const bool rv = (yr0 >= 0) && (yr0 < NH);
    const int yr  = rv ? yr0 : i;       // clamp: garbage summed, masked at the end

    // channel walk: c = q, q+2, q+4, ... (fronts of the two halves stay 16 KB apart)
    const size_t cb = (size_t)(b * NC + q);
    const float* xp = x + (cb * NH + i ) * NW + j0;
    const float* yp = y + (cb * NH + yr) * NW + j0;

    float acc[PATCH][4];
    #pragma unroll
    for (int dj = 0; dj < PATCH; ++dj)
        #pragma unroll
        for (int tt = 0; tt < 4; ++tt) acc[dj][tt] = 0.0f;

    // depth-4 rolling register pipeline (8 loads in flight)
    float4 X[DEPTH], Y[DEPTH];
    #pragma unroll
    for (int d = 0; d < DEPTH; ++d) {
        X[d] = *(const float4*)(xp + (size_t)(2 * d) * CHST);
        Y[d] = *(const float4*)(yp + (size_t)(2 * d) * CHST);
    }

    #pragma unroll 4
    for (int c = 0; c < NC / 2; ++c) {
        const int k = c & (DEPTH - 1);
        const float4 xa = X[k];
        const float4 ya = Y[k];

        const int cn = (c + DEPTH < NC / 2) ? (c + DEPTH) : c;
        X[k] = *(const float4*)(xp + (size_t)(2 * cn) * CHST);
        Y[k] = *(const float4*)(yp + (size_t)(2 * cn) * CHST);

        // 12-float window [j0-4, j0+8): neighbors via DPP, edges auto-zero
        float wnd[12];
        wnd[0]  = from_prev_lane(ya.x);  wnd[1]  = from_prev_lane(ya.y);
        wnd[2]  = from_prev_lane(ya.z);  wnd[3]  = from_prev_lane(ya.w);
        wnd[4]  = ya.x;                  wnd[5]  = ya.y;
        wnd[6]  = ya.z;                  wnd[7]  = ya.w;
        wnd[8]  = from_next_lane(ya.x);  wnd[9]  = from_next_lane(ya.y);
        wnd[10] = from_next_lane(ya.z);  wnd[11] = from_next_lane(ya.w);

        const float xs[4] = {xa.x, xa.y, xa.z, xa.w};
        #pragma unroll
        for (int dj = 0; dj < PATCH; ++dj)
            #pragma unroll
            for (int tt = 0; tt < 4; ++tt)
                acc[dj][tt] = fmaf(xs[tt], wnd[tt + dj], acc[dj][tt]);
    }

    // cross-parity reduction through LDS (single barrier in the whole kernel)
    if (q == 1) {
        const int l = tid - 192;
        #pragma unroll
        for (int dj = 0; dj < PATCH; ++dj)
            *(float4*)&red[(dj * 192 + l) * 4] =
                make_float4(acc[dj][0], acc[dj][1], acc[dj][2], acc[dj][3]);
    }
    __syncthreads();
    if (q == 0) {
        // rv identical for the partner thread (same di,i) -> mask after sum
        const float sc = rv ? (1.0f / (float)NC) : 0.0f;
        float* op = out + (((size_t)b * (PATCH * PATCH) + di * PATCH) * NH + i) * NW + j0;
        #pragma unroll
        for (int dj = 0; dj < PATCH; ++dj) {
            const float4 r = *(const float4*)&red[(dj * 192 + tid) * 4];
            float4 o = make_float4((acc[dj][0] + r.x) * sc,
                                   (acc[dj][1] + r.y) * sc,
                                   (acc[dj][2] + r.z) * sc,
                                   (acc[dj][3] + r.w) * sc);
            *(float4*)(op + (size_t)dj * CHST) = o;
        }
    }
}

extern "C" void kernel_launch(void* const* d_in, const int* in_sizes, int n_in,
                              void* d_out, int out_size, void* d_ws, size_t ws_size,
                              hipStream_t stream)
{
    const float* x = (const float*)d_in[0];
    const float* y = (const float*)d_in[1];
    float* out = (float*)d_out;

    dim3 grid(NB * (NH / TROWS) * 3);   // (b,t) major, g minor -> x-sharing blocks adjacent
    dim3 block(BT);                     // 6 waves
    hipLaunchKernelGGL(corr_kernel, grid, block, 0, stream, x, y, out);
}